// Round 7
// baseline (343.925 us; speedup 1.0000x reference)
//
#include <hip/hip_runtime.h>
#include <hip/hip_cooperative_groups.h>
#include <math.h>

#define NEG_SLOPE 0.2f
#define XROW 136         // 128 + 8 bf16 pad -> bank-conflict-free frag reads
#define BSHIFT 4         // bucket = dst >> 4  (16 nodes per bucket)
#define BNODES 16
#define NBUCK_MAX 3200   // LDS bound (nbuck = 3125)
#define CAP 768          // ebuf slots per bucket (mean 512, +11 sigma)
#define NHB 256          // edge-pipeline blocks (cooperative, 1/CU)

namespace cg = cooperative_groups;

typedef __attribute__((ext_vector_type(8))) short short8;
typedef __attribute__((ext_vector_type(4))) float floatx4;

__device__ __forceinline__ unsigned short f2bf(float f) {
    unsigned int u = __float_as_uint(f);
    u += 0x7fffu + ((u >> 16) & 1u);          // round-to-nearest-even
    return (unsigned short)(u >> 16);
}
__device__ __forceinline__ float bf2f(unsigned short b) {
    return __uint_as_float(((unsigned int)b) << 16);
}
__device__ __forceinline__ float u2fl(unsigned int u) {
    return __uint_as_float(u << 16);
}
__device__ __forceinline__ float u2fh(unsigned int u) {
    return __uint_as_float(u & 0xffff0000u);
}

// accumulate 8 bf16 feats (packed in uint4) scaled by wt into a[o..o+7]
__device__ __forceinline__ void fma8(float* a, int o, float wt, const uint4& hv) {
    a[o + 0] = fmaf(wt, u2fl(hv.x), a[o + 0]);
    a[o + 1] = fmaf(wt, u2fh(hv.x), a[o + 1]);
    a[o + 2] = fmaf(wt, u2fl(hv.y), a[o + 2]);
    a[o + 3] = fmaf(wt, u2fh(hv.y), a[o + 3]);
    a[o + 4] = fmaf(wt, u2fl(hv.z), a[o + 4]);
    a[o + 5] = fmaf(wt, u2fh(hv.z), a[o + 5]);
    a[o + 6] = fmaf(wt, u2fl(hv.w), a[o + 6]);
    a[o + 7] = fmaf(wt, u2fh(hv.w), a[o + 7]);
}

// edges per pipeline block, rounded to a multiple of 4 for int4 alignment
__device__ __forceinline__ int eph_of(int e) {
    return (((e + NHB - 1) / NHB) + 3) & ~3;
}

// ---------------------------------------------------------------------------
// edge_pipeline (cooperative, NHB=256 blocks): fuses r6's hist_prep + scan +
// scatter into one kernel (2 grid syncs instead of 2 kernel boundaries).
//  P0: W fp32 -> W^T hi/lo bf16 split (first 16384 threads).
//  P1: per-block LDS histogram of its ~6250-edge slice -> C[blk][bucket].
//  P2: thread-per-bucket exclusive scan of C columns -> offsets + btot.
//  P3: per-block LDS cursors from C row; place edges at deterministic
//      disjoint positions. Zero contended global atomics anywhere.
// ---------------------------------------------------------------------------
__global__ __launch_bounds__(256) void edge_pipeline_kernel(
    const float* __restrict__ W, unsigned short* __restrict__ WThi,
    unsigned short* __restrict__ WTlo, const int* __restrict__ src,
    const int* __restrict__ dst, int* __restrict__ C,
    int* __restrict__ btot, int* __restrict__ ebuf, int e, int nbuck)
{
    __shared__ int cnt[NBUCK_MAX];
    cg::grid_group grid = cg::this_grid();
    const int t = threadIdx.x;
    const int blk = blockIdx.x;
    const int gid = blk * 256 + t;

    // ---- P0: W split ----
    if (gid < 16384) {
        const int j = gid >> 7, k = gid & 127;
        const float w = W[k * 128 + j];
        const unsigned short hi = f2bf(w);
        WThi[gid] = hi;
        WTlo[gid] = f2bf(w - bf2f(hi));
    }

    // ---- P1: histogram own slice ----
    for (int b = t; b < nbuck; b += 256) cnt[b] = 0;
    __syncthreads();
    const int eph = eph_of(e);
    const int base = blk * eph;
    const int m = min(e - base, eph);
    if (m > 0) {
        const int m4 = m >> 2;
        for (int j = t; j < m4; j += 256) {
            const int4 d4 = *(const int4*)(dst + base + j * 4);
            atomicAdd(&cnt[d4.x >> BSHIFT], 1);
            atomicAdd(&cnt[d4.y >> BSHIFT], 1);
            atomicAdd(&cnt[d4.z >> BSHIFT], 1);
            atomicAdd(&cnt[d4.w >> BSHIFT], 1);
        }
        for (int j = m4 * 4 + t; j < m; j += 256)
            atomicAdd(&cnt[dst[base + j] >> BSHIFT], 1);
    }
    __syncthreads();
    for (int b = t; b < nbuck; b += 256)
        C[(size_t)blk * nbuck + b] = cnt[b];

    __threadfence();
    grid.sync();

    // ---- P2: exclusive scan per bucket (coalesced row reads) ----
    if (gid < nbuck) {
        int off = 0;
        #pragma unroll 4
        for (int k = 0; k < NHB; ++k) {
            const int v = C[(size_t)k * nbuck + gid];
            C[(size_t)k * nbuck + gid] = off;
            off += v;
        }
        btot[gid] = off;
    }

    __threadfence();
    grid.sync();

    // ---- P3: scatter into deterministic disjoint ranges ----
    for (int b = t; b < nbuck; b += 256)
        cnt[b] = b * CAP + C[(size_t)blk * nbuck + b];
    __syncthreads();
    if (m > 0) {
        const int m4 = m >> 2;
        for (int j = t; j < m4; j += 256) {
            const int i0 = base + j * 4;
            const int4 s4 = *(const int4*)(src + i0);
            const int4 d4 = *(const int4*)(dst + i0);
            int bk, pos;
            bk = d4.x >> BSHIFT; pos = atomicAdd(&cnt[bk], 1);
            if (pos < bk * CAP + CAP) ebuf[pos] = s4.x | ((d4.x & 15) << 16);
            bk = d4.y >> BSHIFT; pos = atomicAdd(&cnt[bk], 1);
            if (pos < bk * CAP + CAP) ebuf[pos] = s4.y | ((d4.y & 15) << 16);
            bk = d4.z >> BSHIFT; pos = atomicAdd(&cnt[bk], 1);
            if (pos < bk * CAP + CAP) ebuf[pos] = s4.z | ((d4.z & 15) << 16);
            bk = d4.w >> BSHIFT; pos = atomicAdd(&cnt[bk], 1);
            if (pos < bk * CAP + CAP) ebuf[pos] = s4.w | ((d4.w & 15) << 16);
        }
        for (int j = m4 * 4 + t; j < m; j += 256) {
            const int d = dst[base + j];
            const int bk = d >> BSHIFT;
            const int pos = atomicAdd(&cnt[bk], 1);
            if (pos < bk * CAP + CAP) ebuf[pos] = src[base + j] | ((d & 15) << 16);
        }
    }
}

// ---------------------------------------------------------------------------
// GEMM: h_bf16 = bf16(x @ W) via 3-MFMA split, fp32 accum, fused es/ed
// epilogue. __launch_bounds__(256,4) -> 128-VGPR cap so the 16 B-fragments
// (64 VGPRs of W^T) stay RESIDENT (r1-r6 ran at 56 VGPRs: compiler re-read
// W from global inside the MFMA loop -> latency-bound at ~2% MfmaUtil).
// Staging issues all 4 x-loads before converting (1 latency, not 4).
// ---------------------------------------------------------------------------
__global__ __launch_bounds__(256, 4) void mfma_gemm_kernel(
    const float* __restrict__ x, const unsigned short* __restrict__ WThi,
    const unsigned short* __restrict__ WTlo, const float* __restrict__ a_src,
    const float* __restrict__ a_dst, unsigned short* __restrict__ hb,
    float* __restrict__ es, float* __restrict__ ed, int n)
{
    __shared__ unsigned short Xhi[32 * XROW];
    __shared__ unsigned short Xlo[32 * XROW];
    const int t = threadIdx.x;
    const int wv = t >> 6, lane = t & 63;
    const int l16 = lane & 15, quad = lane >> 4;
    const int node_base = blockIdx.x * 32;

    // stage X tile: issue 4 independent loads, then convert+store
    float4 xv[4];
    #pragma unroll
    for (int it = 0; it < 4; ++it) {
        const int i = t + it * 256;               // 0..1023
        const int nd = i >> 5, k4 = i & 31;
        float4 v = make_float4(0.f, 0.f, 0.f, 0.f);
        if (node_base + nd < n)
            v = ((const float4*)(x + (size_t)(node_base + nd) * 128))[k4];
        xv[it] = v;
    }
    #pragma unroll
    for (int it = 0; it < 4; ++it) {
        const int i = t + it * 256;
        const int nd = i >> 5, k4 = i & 31;
        const float4 v = xv[it];
        const unsigned short h0 = f2bf(v.x), h1 = f2bf(v.y),
                             h2 = f2bf(v.z), h3 = f2bf(v.w);
        const unsigned short l0 = f2bf(v.x - bf2f(h0)), l1 = f2bf(v.y - bf2f(h1)),
                             l2 = f2bf(v.z - bf2f(h2)), l3 = f2bf(v.w - bf2f(h3));
        *(ushort4*)&Xhi[nd * XROW + k4 * 4] = make_ushort4(h0, h1, h2, h3);
        *(ushort4*)&Xlo[nd * XROW + k4 * 4] = make_ushort4(l0, l1, l2, l3);
    }

    // preload B-frags (wave-invariant W^T rows) -- resident in VGPRs
    short8 bh[4][2], bl[4][2];
    #pragma unroll
    for (int c = 0; c < 4; ++c) {
        #pragma unroll
        for (int u = 0; u < 2; ++u) {
            const int j = (wv * 2 + u) * 16 + l16;
            const int ko = c * 32 + quad * 8;
            bh[c][u] = *(const short8*)&WThi[j * 128 + ko];
            bl[c][u] = *(const short8*)&WTlo[j * 128 + ko];
        }
    }
    __syncthreads();

    floatx4 acc[2][2] = {};
    #pragma unroll
    for (int c = 0; c < 4; ++c) {
        const int ko = c * 32 + quad * 8;
        short8 ah[2], al[2];
        #pragma unroll
        for (int r = 0; r < 2; ++r) {
            ah[r] = *(const short8*)&Xhi[(r * 16 + l16) * XROW + ko];
            al[r] = *(const short8*)&Xlo[(r * 16 + l16) * XROW + ko];
        }
        #pragma unroll
        for (int r = 0; r < 2; ++r)
        #pragma unroll
        for (int u = 0; u < 2; ++u) {
            acc[r][u] = __builtin_amdgcn_mfma_f32_16x16x32_bf16(ah[r], bl[c][u], acc[r][u], 0, 0, 0);
            acc[r][u] = __builtin_amdgcn_mfma_f32_16x16x32_bf16(al[r], bh[c][u], acc[r][u], 0, 0, 0);
            acc[r][u] = __builtin_amdgcn_mfma_f32_16x16x32_bf16(ah[r], bh[c][u], acc[r][u], 0, 0, 0);
        }
    }

    float asv[2], adv[2];
    #pragma unroll
    for (int u = 0; u < 2; ++u) {
        const int feat = (wv * 2 + u) * 16 + l16;
        asv[u] = a_src[feat];
        adv[u] = a_dst[feat];
    }
    #pragma unroll
    for (int r = 0; r < 2; ++r) {
        #pragma unroll
        for (int u = 0; u < 2; ++u) {
            const int feat = (wv * 2 + u) * 16 + l16;
            #pragma unroll
            for (int g = 0; g < 4; ++g) {
                const int node = node_base + r * 16 + quad * 4 + g;
                if (node < n)
                    hb[(size_t)node * 128 + feat] = f2bf(acc[r][u][g]);
            }
        }
        #pragma unroll
        for (int g = 0; g < 4; ++g) {
            float ps = acc[r][0][g] * asv[0] + acc[r][1][g] * asv[1];
            float pd = acc[r][0][g] * adv[0] + acc[r][1][g] * adv[1];
            #pragma unroll
            for (int o = 8; o >= 1; o >>= 1) {
                ps += __shfl_xor(ps, o);
                pd += __shfl_xor(pd, o);
            }
            const int node = node_base + r * 16 + quad * 4 + g;
            if (l16 == 0 && node < n) {
                es[node * 4 + wv] = ps;   // head == wv
                ed[node * 4 + wv] = pd;
            }
        }
    }
}

// ---------------------------------------------------------------------------
// sort_agg: one block per 16-node bucket, exact per-bucket region
// [b*CAP, b*CAP+btot[b]). In-LDS counting sort, then wave wv aggregates
// nodes wv*4..wv*4+3: 8 lanes/edge (lane owns 16 feats), 16 edges in
// flight per wave. (Unchanged from r6: measured 60 us.)
// ---------------------------------------------------------------------------
__global__ __launch_bounds__(256) void sort_agg_kernel(
    const unsigned short* __restrict__ hb, const float* __restrict__ es,
    const float* __restrict__ ed, const float* __restrict__ bias,
    const int* __restrict__ btot, const int* __restrict__ ebuf,
    float* __restrict__ out, int n)
{
    __shared__ unsigned short esort[CAP];
    __shared__ int hist[BNODES], hexcl[BNODES], cur[BNODES];
    const int b = blockIdx.x;
    const int t = threadIdx.x;
    const int lane = t & 63;
    const int wv = t >> 6;
    const int l8 = lane & 7;
    const int oct = lane >> 3;
    const int f0 = l8 * 16;      // this lane's 16 output features
    const int hh = l8 >> 1;      // head of those features (constant)

    const int start = b * CAP;
    const int end = start + min(btot[b], CAP);

    if (t < BNODES) hist[t] = 0;
    __syncthreads();
    for (int i = start + t; i < end; i += 256)
        atomicAdd(&hist[(ebuf[i] >> 16) & (BNODES - 1)], 1);
    __syncthreads();
    if (wv == 0) {
        const int v = (lane < BNODES) ? hist[lane] : 0;
        int incl = v;
        #pragma unroll
        for (int o = 1; o < BNODES; o <<= 1) {
            const int tt = __shfl_up(incl, o);
            if (lane >= o) incl += tt;
        }
        if (lane < BNODES) { hexcl[lane] = incl - v; cur[lane] = incl - v; }
    }
    __syncthreads();
    for (int i = start + t; i < end; i += 256) {
        const int v = ebuf[i];
        const int pos = atomicAdd(&cur[(v >> 16) & (BNODES - 1)], 1);
        if (pos < CAP) esort[pos] = (unsigned short)(v & 0xFFFF);
    }
    __syncthreads();

    // aggregation: wave wv owns nodes wv*4 .. wv*4+3 (sequential)
    for (int j = 0; j < 4; ++j) {
        const int nd = wv * 4 + j;
        const int node = b * BNODES + nd;
        if (node >= n) break;
        const int off = hexcl[nd];
        const int deg = hist[nd];
        const float edh = ed[(size_t)node * 4 + hh];

        float a[16];
        #pragma unroll
        for (int k = 0; k < 16; ++k) a[k] = 0.f;
        float wsum = 0.f;

        for (int c0 = 0; c0 < deg; c0 += 16) {
            const int ci0 = c0 + oct;
            const int ci1 = ci0 + 8;
            const int dm = deg - 1;
            const int s0 = esort[min(off + min(ci0, dm), CAP - 1)];
            const int s1 = esort[min(off + min(ci1, dm), CAP - 1)];
            const float e0 = es[(size_t)s0 * 4 + hh];
            const float e1 = es[(size_t)s1 * 4 + hh];
            const uint4 hA0 = *(const uint4*)&hb[(size_t)s0 * 128 + f0];
            const uint4 hB0 = *(const uint4*)&hb[(size_t)s0 * 128 + f0 + 8];
            const uint4 hA1 = *(const uint4*)&hb[(size_t)s1 * 128 + f0];
            const uint4 hB1 = *(const uint4*)&hb[(size_t)s1 * 128 + f0 + 8];
            float lg0 = e0 + edh; lg0 = lg0 > 0.f ? lg0 : NEG_SLOPE * lg0;
            float lg1 = e1 + edh; lg1 = lg1 > 0.f ? lg1 : NEG_SLOPE * lg1;
            const float w0 = (ci0 < deg) ? __expf(lg0) : 0.f;
            const float w1 = (ci1 < deg) ? __expf(lg1) : 0.f;
            fma8(a, 0, w0, hA0); fma8(a, 8, w0, hB0);
            fma8(a, 0, w1, hA1); fma8(a, 8, w1, hB1);
            wsum += w0 + w1;
        }
        // combine the 8 octs
        #pragma unroll
        for (int o = 8; o <= 32; o <<= 1) {
            #pragma unroll
            for (int k = 0; k < 16; ++k) a[k] += __shfl_xor(a[k], o);
            wsum += __shfl_xor(wsum, o);
        }
        if (oct == 0) {
            const float inv = 1.f / ((wsum > 0.f) ? wsum : 1.f);
            #pragma unroll
            for (int q = 0; q < 4; ++q) {
                const float4 bq = *(const float4*)(bias + f0 + q * 4);
                float4 o4;
                o4.x = a[q * 4 + 0] * inv + bq.x;
                o4.y = a[q * 4 + 1] * inv + bq.y;
                o4.z = a[q * 4 + 2] * inv + bq.z;
                o4.w = a[q * 4 + 3] * inv + bq.w;
                *(float4*)(out + (size_t)node * 128 + f0 + q * 4) = o4;
            }
        }
    }
}

// ---------------------------------------------------------------------------
extern "C" void kernel_launch(void* const* d_in, const int* in_sizes, int n_in,
                              void* d_out, int out_size, void* d_ws, size_t ws_size,
                              hipStream_t stream)
{
    const float* x      = (const float*)d_in[0];
    const float* W      = (const float*)d_in[1];
    const float* a_src  = (const float*)d_in[2];
    const float* a_dst  = (const float*)d_in[3];
    const float* bias   = (const float*)d_in[4];
    const int*   e_src  = (const int*)d_in[5];
    const int*   e_dst  = (const int*)d_in[6];
    float* out = (float*)d_out;

    const int n = in_sizes[0] / 128;             // 50000 (< 65536: src fits 16b)
    int e = in_sizes[5];                         // 1600000
    int nbuck = (n + BNODES - 1) >> BSHIFT;      // 3125

    char* ws = (char*)d_ws;
    size_t o = 0;
    auto alloc = [&](size_t bytes) { void* p = ws + o; o += (bytes + 255) & ~(size_t)255; return p; };
    unsigned short* hb   = (unsigned short*)alloc((size_t)n * 128 * sizeof(unsigned short)); // 12.8 MB
    unsigned short* WThi = (unsigned short*)alloc(128 * 128 * sizeof(unsigned short));
    unsigned short* WTlo = (unsigned short*)alloc(128 * 128 * sizeof(unsigned short));
    float* es      = (float*)alloc((size_t)n * 4 * sizeof(float));
    float* ed      = (float*)alloc((size_t)n * 4 * sizeof(float));
    int* C         = (int*)alloc((size_t)NHB * nbuck * sizeof(int));   // 3.2 MB
    int* btot      = (int*)alloc((size_t)nbuck * sizeof(int));         // 12.5 KB
    int* ebuf      = (int*)alloc((size_t)nbuck * CAP * sizeof(int));   // 9.6 MB
    (void)ws_size; (void)n_in; (void)out_size;

    void* args[] = {(void*)&W, (void*)&WThi, (void*)&WTlo, (void*)&e_src,
                    (void*)&e_dst, (void*)&C, (void*)&btot, (void*)&ebuf,
                    (void*)&e, (void*)&nbuck};
    hipLaunchCooperativeKernel((const void*)edge_pipeline_kernel,
                               dim3(NHB), dim3(256), args, 0, stream);
    mfma_gemm_kernel<<<(n + 31) / 32, 256, 0, stream>>>(x, WThi, WTlo, a_src, a_dst,
                                                        hb, es, ed, n);
    sort_agg_kernel<<<nbuck, 256, 0, stream>>>(hb, es, ed, bias, btot, ebuf, out, n);
}

// Round 8
// 214.983 us; speedup vs baseline: 1.5998x; 1.5998x over previous
//
#include <hip/hip_runtime.h>
#include <math.h>

#define NEG_SLOPE 0.2f
#define XROW 136         // 128 + 8 bf16 pad -> bank-conflict-free frag reads
#define BSHIFT 4         // bucket = dst >> 4  (16 nodes per bucket)
#define BNODES 16
#define NBUCK_MAX 3200   // LDS bound (nbuck = 3125)
#define CAP 768          // ebuf slots per bucket (mean 512, +11 sigma)
#define CPAD 32          // ints per global cursor (one 128B line each)
#define NSB 256          // scatter blocks (1024 threads each)
#define STASH 6272       // >= ceil(1.6e6/256)=6250 rounded up

typedef __attribute__((ext_vector_type(8))) short short8;
typedef __attribute__((ext_vector_type(4))) float floatx4;

__device__ __forceinline__ unsigned short f2bf(float f) {
    unsigned int u = __float_as_uint(f);
    u += 0x7fffu + ((u >> 16) & 1u);          // round-to-nearest-even
    return (unsigned short)(u >> 16);
}
__device__ __forceinline__ float bf2f(unsigned short b) {
    return __uint_as_float(((unsigned int)b) << 16);
}
__device__ __forceinline__ float u2fl(unsigned int u) {
    return __uint_as_float(u << 16);
}
__device__ __forceinline__ float u2fh(unsigned int u) {
    return __uint_as_float(u & 0xffff0000u);
}

// accumulate 8 bf16 feats (packed in uint4) scaled by wt into a[o..o+7]
__device__ __forceinline__ void fma8(float* a, int o, float wt, const uint4& hv) {
    a[o + 0] = fmaf(wt, u2fl(hv.x), a[o + 0]);
    a[o + 1] = fmaf(wt, u2fh(hv.x), a[o + 1]);
    a[o + 2] = fmaf(wt, u2fl(hv.y), a[o + 2]);
    a[o + 3] = fmaf(wt, u2fh(hv.y), a[o + 3]);
    a[o + 4] = fmaf(wt, u2fl(hv.z), a[o + 4]);
    a[o + 5] = fmaf(wt, u2fh(hv.z), a[o + 5]);
    a[o + 6] = fmaf(wt, u2fl(hv.w), a[o + 6]);
    a[o + 7] = fmaf(wt, u2fh(hv.w), a[o + 7]);
}

// ---------------------------------------------------------------------------
// Prep: W [k][j] fp32 -> W^T hi/lo bf16 [j][k] (error-compensated split);
// init per-bucket line-padded global cursors gcur[b*CPAD] = b*CAP.
// ---------------------------------------------------------------------------
__global__ __launch_bounds__(256) void prep_w_kernel(
    const float* __restrict__ W, unsigned short* __restrict__ WThi,
    unsigned short* __restrict__ WTlo, int* __restrict__ gcur, int nbuck)
{
    const int idx = blockIdx.x * 256 + threadIdx.x;  // j*128 + k
    const int j = idx >> 7, k = idx & 127;
    const float w = W[k * 128 + j];
    const unsigned short hi = f2bf(w);
    WThi[idx] = hi;
    WTlo[idx] = f2bf(w - bf2f(hi));
    if (idx < nbuck) gcur[idx * CPAD] = idx * CAP;
}

// ---------------------------------------------------------------------------
// scatter: 256 blocks x 1024 threads (16 waves/CU -- r7 showed 256-thread
// 1-block/CU runs at 1 wave/SIMD with zero latency hiding). Per block:
// stash own ~6250-edge slice packed in LDS + LDS-count per bucket; claim a
// contiguous run per (block,bucket) with ONE global atomic on a LINE-PADDED
// cursor (400k atomics over 3125 independent lines; ~12 RMW/cyc device
// ceiling => ~14us, overlapped since blocks are unsynchronized); place via
// LDS cursors. Pack: src[0:16) | ldst[16:20) | bucket[20:32).
// ---------------------------------------------------------------------------
__global__ __launch_bounds__(1024) void scatter_kernel(
    const int* __restrict__ src, const int* __restrict__ dst,
    int* __restrict__ gcur, int* __restrict__ ebuf, int e, int nbuck)
{
    __shared__ unsigned int stash[STASH];
    __shared__ int cnt[NBUCK_MAX];
    const int t = threadIdx.x;
    for (int b = t; b < nbuck; b += 1024) cnt[b] = 0;
    __syncthreads();
    const int eph = (((e + NSB - 1) / NSB) + 3) & ~3;
    const int base = blockIdx.x * eph;
    const int m = min(e - base, eph);
    if (m > 0) {
        const int m4 = m >> 2;
        for (int j = t; j < m4; j += 1024) {
            const int i0 = base + j * 4;
            const int4 s4 = *(const int4*)(src + i0);
            const int4 d4 = *(const int4*)(dst + i0);
            stash[j * 4 + 0] = (unsigned)s4.x | ((unsigned)(d4.x & 15) << 16)
                             | ((unsigned)(d4.x >> BSHIFT) << 20);
            atomicAdd(&cnt[d4.x >> BSHIFT], 1);
            stash[j * 4 + 1] = (unsigned)s4.y | ((unsigned)(d4.y & 15) << 16)
                             | ((unsigned)(d4.y >> BSHIFT) << 20);
            atomicAdd(&cnt[d4.y >> BSHIFT], 1);
            stash[j * 4 + 2] = (unsigned)s4.z | ((unsigned)(d4.z & 15) << 16)
                             | ((unsigned)(d4.z >> BSHIFT) << 20);
            atomicAdd(&cnt[d4.z >> BSHIFT], 1);
            stash[j * 4 + 3] = (unsigned)s4.w | ((unsigned)(d4.w & 15) << 16)
                             | ((unsigned)(d4.w >> BSHIFT) << 20);
            atomicAdd(&cnt[d4.w >> BSHIFT], 1);
        }
        for (int j = m4 * 4 + t; j < m; j += 1024) {
            const int d = dst[base + j];
            stash[j] = (unsigned)src[base + j] | ((unsigned)(d & 15) << 16)
                     | ((unsigned)(d >> BSHIFT) << 20);
            atomicAdd(&cnt[d >> BSHIFT], 1);
        }
    }
    __syncthreads();
    // claim: one padded global atomic per occupied (block,bucket);
    // cnt[b] becomes this block's global write base for bucket b.
    for (int b = t; b < nbuck; b += 1024) {
        const int c = cnt[b];
        if (c > 0) cnt[b] = atomicAdd(&gcur[b * CPAD], c);
    }
    __syncthreads();
    // place
    for (int j = t; j < m; j += 1024) {
        const unsigned int v = stash[j];
        const int bk = v >> 20;
        const int pos = atomicAdd(&cnt[bk], 1);
        if (pos < bk * CAP + CAP) ebuf[pos] = (int)(v & 0xFFFFFu);
    }
}

// ---------------------------------------------------------------------------
// GEMM: h_bf16 = bf16(x @ W) via 3-MFMA split, fp32 accum, fused es/ed
// epilogue. __launch_bounds__(256,2) -> 256-VGPR cap: the 16 B-fragments
// (64 VGPRs of W^T) stay RESIDENT without spilling (r1-r6 ran at 56 VGPR:
// B re-read from memory inside the MFMA loop, MfmaUtil ~2%; r7's (256,4)
// capped at 128 VGPR and spilled to scratch, worse).
// ---------------------------------------------------------------------------
__global__ __launch_bounds__(256, 2) void mfma_gemm_kernel(
    const float* __restrict__ x, const unsigned short* __restrict__ WThi,
    const unsigned short* __restrict__ WTlo, const float* __restrict__ a_src,
    const float* __restrict__ a_dst, unsigned short* __restrict__ hb,
    float* __restrict__ es, float* __restrict__ ed, int n)
{
    __shared__ unsigned short Xhi[32 * XROW];
    __shared__ unsigned short Xlo[32 * XROW];
    const int t = threadIdx.x;
    const int wv = t >> 6, lane = t & 63;
    const int l16 = lane & 15, quad = lane >> 4;
    const int node_base = blockIdx.x * 32;

    // stage X tile: issue 4 independent loads, then convert+store
    float4 xv[4];
    #pragma unroll
    for (int it = 0; it < 4; ++it) {
        const int i = t + it * 256;               // 0..1023
        const int nd = i >> 5, k4 = i & 31;
        float4 v = make_float4(0.f, 0.f, 0.f, 0.f);
        if (node_base + nd < n)
            v = ((const float4*)(x + (size_t)(node_base + nd) * 128))[k4];
        xv[it] = v;
    }
    #pragma unroll
    for (int it = 0; it < 4; ++it) {
        const int i = t + it * 256;
        const int nd = i >> 5, k4 = i & 31;
        const float4 v = xv[it];
        const unsigned short h0 = f2bf(v.x), h1 = f2bf(v.y),
                             h2 = f2bf(v.z), h3 = f2bf(v.w);
        const unsigned short l0 = f2bf(v.x - bf2f(h0)), l1 = f2bf(v.y - bf2f(h1)),
                             l2 = f2bf(v.z - bf2f(h2)), l3 = f2bf(v.w - bf2f(h3));
        *(ushort4*)&Xhi[nd * XROW + k4 * 4] = make_ushort4(h0, h1, h2, h3);
        *(ushort4*)&Xlo[nd * XROW + k4 * 4] = make_ushort4(l0, l1, l2, l3);
    }

    // preload B-frags (wave-invariant W^T rows) -- resident in VGPRs
    short8 bh[4][2], bl[4][2];
    #pragma unroll
    for (int c = 0; c < 4; ++c) {
        #pragma unroll
        for (int u = 0; u < 2; ++u) {
            const int j = (wv * 2 + u) * 16 + l16;
            const int ko = c * 32 + quad * 8;
            bh[c][u] = *(const short8*)&WThi[j * 128 + ko];
            bl[c][u] = *(const short8*)&WTlo[j * 128 + ko];
        }
    }
    __syncthreads();

    floatx4 acc[2][2] = {};
    #pragma unroll
    for (int c = 0; c < 4; ++c) {
        const int ko = c * 32 + quad * 8;
        short8 ah[2], al[2];
        #pragma unroll
        for (int r = 0; r < 2; ++r) {
            ah[r] = *(const short8*)&Xhi[(r * 16 + l16) * XROW + ko];
            al[r] = *(const short8*)&Xlo[(r * 16 + l16) * XROW + ko];
        }
        #pragma unroll
        for (int r = 0; r < 2; ++r)
        #pragma unroll
        for (int u = 0; u < 2; ++u) {
            acc[r][u] = __builtin_amdgcn_mfma_f32_16x16x32_bf16(ah[r], bl[c][u], acc[r][u], 0, 0, 0);
            acc[r][u] = __builtin_amdgcn_mfma_f32_16x16x32_bf16(al[r], bh[c][u], acc[r][u], 0, 0, 0);
            acc[r][u] = __builtin_amdgcn_mfma_f32_16x16x32_bf16(ah[r], bh[c][u], acc[r][u], 0, 0, 0);
        }
    }

    float asv[2], adv[2];
    #pragma unroll
    for (int u = 0; u < 2; ++u) {
        const int feat = (wv * 2 + u) * 16 + l16;
        asv[u] = a_src[feat];
        adv[u] = a_dst[feat];
    }
    #pragma unroll
    for (int r = 0; r < 2; ++r) {
        #pragma unroll
        for (int u = 0; u < 2; ++u) {
            const int feat = (wv * 2 + u) * 16 + l16;
            #pragma unroll
            for (int g = 0; g < 4; ++g) {
                const int node = node_base + r * 16 + quad * 4 + g;
                if (node < n)
                    hb[(size_t)node * 128 + feat] = f2bf(acc[r][u][g]);
            }
        }
        #pragma unroll
        for (int g = 0; g < 4; ++g) {
            float ps = acc[r][0][g] * asv[0] + acc[r][1][g] * asv[1];
            float pd = acc[r][0][g] * adv[0] + acc[r][1][g] * adv[1];
            #pragma unroll
            for (int o = 8; o >= 1; o >>= 1) {
                ps += __shfl_xor(ps, o);
                pd += __shfl_xor(pd, o);
            }
            const int node = node_base + r * 16 + quad * 4 + g;
            if (l16 == 0 && node < n) {
                es[node * 4 + wv] = ps;   // head == wv
                ed[node * 4 + wv] = pd;
            }
        }
    }
}

// ---------------------------------------------------------------------------
// sort_agg: one block per 16-node bucket, region [b*CAP, gcur[b*CPAD]).
// In-LDS counting sort, then wave wv aggregates nodes wv*4..wv*4+3:
// 8 lanes/edge (lane owns 16 feats), 16 edges in flight per wave.
// (r6 form, measured 60us.)
// ---------------------------------------------------------------------------
__global__ __launch_bounds__(256) void sort_agg_kernel(
    const unsigned short* __restrict__ hb, const float* __restrict__ es,
    const float* __restrict__ ed, const float* __restrict__ bias,
    const int* __restrict__ gcur, const int* __restrict__ ebuf,
    float* __restrict__ out, int n)
{
    __shared__ unsigned short esort[CAP];
    __shared__ int hist[BNODES], hexcl[BNODES], cur[BNODES];
    const int b = blockIdx.x;
    const int t = threadIdx.x;
    const int lane = t & 63;
    const int wv = t >> 6;
    const int l8 = lane & 7;
    const int oct = lane >> 3;
    const int f0 = l8 * 16;      // this lane's 16 output features
    const int hh = l8 >> 1;      // head of those features (constant)

    const int start = b * CAP;
    const int end = start + min(gcur[b * CPAD] - start, CAP);

    if (t < BNODES) hist[t] = 0;
    __syncthreads();
    for (int i = start + t; i < end; i += 256)
        atomicAdd(&hist[(ebuf[i] >> 16) & (BNODES - 1)], 1);
    __syncthreads();
    if (wv == 0) {
        const int v = (lane < BNODES) ? hist[lane] : 0;
        int incl = v;
        #pragma unroll
        for (int o = 1; o < BNODES; o <<= 1) {
            const int tt = __shfl_up(incl, o);
            if (lane >= o) incl += tt;
        }
        if (lane < BNODES) { hexcl[lane] = incl - v; cur[lane] = incl - v; }
    }
    __syncthreads();
    for (int i = start + t; i < end; i += 256) {
        const int v = ebuf[i];
        const int pos = atomicAdd(&cur[(v >> 16) & (BNODES - 1)], 1);
        if (pos < CAP) esort[pos] = (unsigned short)(v & 0xFFFF);
    }
    __syncthreads();

    // aggregation: wave wv owns nodes wv*4 .. wv*4+3 (sequential)
    for (int j = 0; j < 4; ++j) {
        const int nd = wv * 4 + j;
        const int node = b * BNODES + nd;
        if (node >= n) break;
        const int off = hexcl[nd];
        const int deg = hist[nd];
        const float edh = ed[(size_t)node * 4 + hh];

        float a[16];
        #pragma unroll
        for (int k = 0; k < 16; ++k) a[k] = 0.f;
        float wsum = 0.f;

        for (int c0 = 0; c0 < deg; c0 += 16) {
            const int ci0 = c0 + oct;
            const int ci1 = ci0 + 8;
            const int dm = deg - 1;
            const int s0 = esort[min(off + min(ci0, dm), CAP - 1)];
            const int s1 = esort[min(off + min(ci1, dm), CAP - 1)];
            const float e0 = es[(size_t)s0 * 4 + hh];
            const float e1 = es[(size_t)s1 * 4 + hh];
            const uint4 hA0 = *(const uint4*)&hb[(size_t)s0 * 128 + f0];
            const uint4 hB0 = *(const uint4*)&hb[(size_t)s0 * 128 + f0 + 8];
            const uint4 hA1 = *(const uint4*)&hb[(size_t)s1 * 128 + f0];
            const uint4 hB1 = *(const uint4*)&hb[(size_t)s1 * 128 + f0 + 8];
            float lg0 = e0 + edh; lg0 = lg0 > 0.f ? lg0 : NEG_SLOPE * lg0;
            float lg1 = e1 + edh; lg1 = lg1 > 0.f ? lg1 : NEG_SLOPE * lg1;
            const float w0 = (ci0 < deg) ? __expf(lg0) : 0.f;
            const float w1 = (ci1 < deg) ? __expf(lg1) : 0.f;
            fma8(a, 0, w0, hA0); fma8(a, 8, w0, hB0);
            fma8(a, 0, w1, hA1); fma8(a, 8, w1, hB1);
            wsum += w0 + w1;
        }
        // combine the 8 octs
        #pragma unroll
        for (int o = 8; o <= 32; o <<= 1) {
            #pragma unroll
            for (int k = 0; k < 16; ++k) a[k] += __shfl_xor(a[k], o);
            wsum += __shfl_xor(wsum, o);
        }
        if (oct == 0) {
            const float inv = 1.f / ((wsum > 0.f) ? wsum : 1.f);
            #pragma unroll
            for (int q = 0; q < 4; ++q) {
                const float4 bq = *(const float4*)(bias + f0 + q * 4);
                float4 o4;
                o4.x = a[q * 4 + 0] * inv + bq.x;
                o4.y = a[q * 4 + 1] * inv + bq.y;
                o4.z = a[q * 4 + 2] * inv + bq.z;
                o4.w = a[q * 4 + 3] * inv + bq.w;
                *(float4*)(out + (size_t)node * 128 + f0 + q * 4) = o4;
            }
        }
    }
}

// ---------------------------------------------------------------------------
extern "C" void kernel_launch(void* const* d_in, const int* in_sizes, int n_in,
                              void* d_out, int out_size, void* d_ws, size_t ws_size,
                              hipStream_t stream)
{
    const float* x      = (const float*)d_in[0];
    const float* W      = (const float*)d_in[1];
    const float* a_src  = (const float*)d_in[2];
    const float* a_dst  = (const float*)d_in[3];
    const float* bias   = (const float*)d_in[4];
    const int*   e_src  = (const int*)d_in[5];
    const int*   e_dst  = (const int*)d_in[6];
    float* out = (float*)d_out;

    const int n = in_sizes[0] / 128;             // 50000 (< 65536: src fits 16b)
    const int e = in_sizes[5];                   // 1600000
    const int nbuck = (n + BNODES - 1) >> BSHIFT; // 3125 (< 4096: fits 12b)

    char* ws = (char*)d_ws;
    size_t o = 0;
    auto alloc = [&](size_t bytes) { void* p = ws + o; o += (bytes + 255) & ~(size_t)255; return p; };
    unsigned short* hb   = (unsigned short*)alloc((size_t)n * 128 * sizeof(unsigned short)); // 12.8 MB
    unsigned short* WThi = (unsigned short*)alloc(128 * 128 * sizeof(unsigned short));
    unsigned short* WTlo = (unsigned short*)alloc(128 * 128 * sizeof(unsigned short));
    float* es      = (float*)alloc((size_t)n * 4 * sizeof(float));
    float* ed      = (float*)alloc((size_t)n * 4 * sizeof(float));
    int* gcur      = (int*)alloc((size_t)nbuck * CPAD * sizeof(int));  // 400 KB
    int* ebuf      = (int*)alloc((size_t)nbuck * CAP * sizeof(int));   // 9.6 MB
    (void)ws_size; (void)n_in; (void)out_size;

    prep_w_kernel<<<64, 256, 0, stream>>>(W, WThi, WTlo, gcur, nbuck);
    scatter_kernel<<<NSB, 1024, 0, stream>>>(e_src, e_dst, gcur, ebuf, e, nbuck);
    mfma_gemm_kernel<<<(n + 31) / 32, 256, 0, stream>>>(x, WThi, WTlo, a_src, a_dst,
                                                        hb, es, ed, n);
    sort_agg_kernel<<<nbuck, 256, 0, stream>>>(hb, es, ed, bias, gcur, ebuf, out, n);
}

// Round 9
// 198.237 us; speedup vs baseline: 1.7349x; 1.0845x over previous
//
#include <hip/hip_runtime.h>
#include <math.h>

#define NEG_SLOPE 0.2f
#define XROW 136         // 128 + 8 bf16 pad -> bank-conflict-free frag reads
#define RSHIFT 6         // region = dst >> 6 (64 nodes)
#define RNODES 64
#define NREG_MAX 800     // LDS bound (nreg = 782)
#define RCAP 2432        // ebuf slots per region (mean 2048, +8.5 sigma)
#define CPAD 32          // ints per global cursor (one 128B line each)
#define NSB 256          // scatter blocks (1024 threads each)
#define STASH 6272       // >= ceil(1.6e6/256)=6250 rounded up

typedef __attribute__((ext_vector_type(8))) short short8;
typedef __attribute__((ext_vector_type(4))) float floatx4;

__device__ __forceinline__ unsigned short f2bf(float f) {
    unsigned int u = __float_as_uint(f);
    u += 0x7fffu + ((u >> 16) & 1u);          // round-to-nearest-even
    return (unsigned short)(u >> 16);
}
__device__ __forceinline__ float bf2f(unsigned short b) {
    return __uint_as_float(((unsigned int)b) << 16);
}
__device__ __forceinline__ float u2fl(unsigned int u) {
    return __uint_as_float(u << 16);
}
__device__ __forceinline__ float u2fh(unsigned int u) {
    return __uint_as_float(u & 0xffff0000u);
}

// accumulate 8 bf16 feats (packed in uint4) scaled by wt into a[o..o+7]
__device__ __forceinline__ void fma8(float* a, int o, float wt, const uint4& hv) {
    a[o + 0] = fmaf(wt, u2fl(hv.x), a[o + 0]);
    a[o + 1] = fmaf(wt, u2fh(hv.x), a[o + 1]);
    a[o + 2] = fmaf(wt, u2fl(hv.y), a[o + 2]);
    a[o + 3] = fmaf(wt, u2fh(hv.y), a[o + 3]);
    a[o + 4] = fmaf(wt, u2fl(hv.z), a[o + 4]);
    a[o + 5] = fmaf(wt, u2fh(hv.z), a[o + 5]);
    a[o + 6] = fmaf(wt, u2fl(hv.w), a[o + 6]);
    a[o + 7] = fmaf(wt, u2fh(hv.w), a[o + 7]);
}

// ---------------------------------------------------------------------------
// Prep: W [k][j] fp32 -> W^T hi/lo bf16 [j][k] (error-compensated split);
// init per-region line-padded global cursors gcur[r*CPAD] = r*RCAP.
// ---------------------------------------------------------------------------
__global__ __launch_bounds__(256) void prep_w_kernel(
    const float* __restrict__ W, unsigned short* __restrict__ WThi,
    unsigned short* __restrict__ WTlo, int* __restrict__ gcur, int nreg)
{
    const int idx = blockIdx.x * 256 + threadIdx.x;  // j*128 + k
    const int j = idx >> 7, k = idx & 127;
    const float w = W[k * 128 + j];
    const unsigned short hi = f2bf(w);
    WThi[idx] = hi;
    WTlo[idx] = f2bf(w - bf2f(hi));
    if (idx < nreg) gcur[idx * CPAD] = idx * RCAP;
}

// ---------------------------------------------------------------------------
// scatter: 256 blocks x 1024 threads. Stash own ~6250-edge slice packed in
// LDS + LDS-count per 64-node REGION (782 regions -> claims = 256x782 =
// 200k global RMWs, vs 690k at 16-node buckets); claim with one padded
// atomic per (block,region), DE-PHASED per block (all blocks hit the claim
// phase simultaneously -- same-order walks convoy on the same line);
// place via LDS cursors. Pack: src[0:16) | ldst[16:22) | region[22:32).
// ---------------------------------------------------------------------------
__global__ __launch_bounds__(1024) void scatter_kernel(
    const int* __restrict__ src, const int* __restrict__ dst,
    int* __restrict__ gcur, int* __restrict__ ebuf, int e, int nreg)
{
    __shared__ unsigned int stash[STASH];
    __shared__ int cnt[NREG_MAX];
    const int t = threadIdx.x;
    for (int b = t; b < nreg; b += 1024) cnt[b] = 0;
    __syncthreads();
    const int eph = (((e + NSB - 1) / NSB) + 3) & ~3;
    const int base = blockIdx.x * eph;
    const int m = min(e - base, eph);
    if (m > 0) {
        const int m4 = m >> 2;
        for (int j = t; j < m4; j += 1024) {
            const int i0 = base + j * 4;
            const int4 s4 = *(const int4*)(src + i0);
            const int4 d4 = *(const int4*)(dst + i0);
            stash[j * 4 + 0] = (unsigned)s4.x | ((unsigned)(d4.x & 63) << 16)
                             | ((unsigned)(d4.x >> RSHIFT) << 22);
            atomicAdd(&cnt[d4.x >> RSHIFT], 1);
            stash[j * 4 + 1] = (unsigned)s4.y | ((unsigned)(d4.y & 63) << 16)
                             | ((unsigned)(d4.y >> RSHIFT) << 22);
            atomicAdd(&cnt[d4.y >> RSHIFT], 1);
            stash[j * 4 + 2] = (unsigned)s4.z | ((unsigned)(d4.z & 63) << 16)
                             | ((unsigned)(d4.z >> RSHIFT) << 22);
            atomicAdd(&cnt[d4.z >> RSHIFT], 1);
            stash[j * 4 + 3] = (unsigned)s4.w | ((unsigned)(d4.w & 63) << 16)
                             | ((unsigned)(d4.w >> RSHIFT) << 22);
            atomicAdd(&cnt[d4.w >> RSHIFT], 1);
        }
        for (int j = m4 * 4 + t; j < m; j += 1024) {
            const int d = dst[base + j];
            stash[j] = (unsigned)src[base + j] | ((unsigned)(d & 63) << 16)
                     | ((unsigned)(d >> RSHIFT) << 22);
            atomicAdd(&cnt[d >> RSHIFT], 1);
        }
    }
    __syncthreads();
    // claim: one padded global atomic per occupied (block,region), de-phased
    {
        const int off0 = (blockIdx.x * 97) % nreg;
        for (int i = t; i < nreg; i += 1024) {
            int b = i + off0;
            if (b >= nreg) b -= nreg;
            const int c = cnt[b];
            if (c > 0) cnt[b] = atomicAdd(&gcur[b * CPAD], c);
        }
    }
    __syncthreads();
    // place
    for (int j = t; j < m; j += 1024) {
        const unsigned int v = stash[j];
        const int bk = v >> 22;
        const int pos = atomicAdd(&cnt[bk], 1);
        if (pos < bk * RCAP + RCAP) ebuf[pos] = (int)(v & 0x3FFFFFu);
    }
}

// ---------------------------------------------------------------------------
// GEMM: h_bf16 = bf16(x @ W) via 3-MFMA split, fp32 accum, fused es/ed
// epilogue. B-WINDOW restructure: u-loop outer holds only 4 hi + 4 lo
// B-frags (32 VGPRs) at a time -> peak ~100 VGPR, so (256,4) = 16 waves/CU
// WITHOUT spill (r7: full 64-VGPR B under a 128 cap spilled; r1-r6: 56-VGPR
// builds re-read B from memory per MFMA, MfmaUtil ~2%). hb is written via
// LDS transpose + uint4 stores (2 VMEM ops/thread instead of 16 scalar 2B).
// ---------------------------------------------------------------------------
__global__ __launch_bounds__(256, 4) void mfma_gemm_kernel(
    const float* __restrict__ x, const unsigned short* __restrict__ WThi,
    const unsigned short* __restrict__ WTlo, const float* __restrict__ a_src,
    const float* __restrict__ a_dst, unsigned short* __restrict__ hb,
    float* __restrict__ es, float* __restrict__ ed, int n)
{
    __shared__ unsigned short Xhi[32 * XROW];
    __shared__ unsigned short Xlo[32 * XROW];
    const int t = threadIdx.x;
    const int wv = t >> 6, lane = t & 63;
    const int l16 = lane & 15, quad = lane >> 4;
    const int node_base = blockIdx.x * 32;

    // stage X tile: issue 4 independent loads, then convert+store
    float4 xv[4];
    #pragma unroll
    for (int it = 0; it < 4; ++it) {
        const int i = t + it * 256;               // 0..1023
        const int nd = i >> 5, k4 = i & 31;
        float4 v = make_float4(0.f, 0.f, 0.f, 0.f);
        if (node_base + nd < n)
            v = ((const float4*)(x + (size_t)(node_base + nd) * 128))[k4];
        xv[it] = v;
    }
    #pragma unroll
    for (int it = 0; it < 4; ++it) {
        const int i = t + it * 256;
        const int nd = i >> 5, k4 = i & 31;
        const float4 v = xv[it];
        const unsigned short h0 = f2bf(v.x), h1 = f2bf(v.y),
                             h2 = f2bf(v.z), h3 = f2bf(v.w);
        const unsigned short l0 = f2bf(v.x - bf2f(h0)), l1 = f2bf(v.y - bf2f(h1)),
                             l2 = f2bf(v.z - bf2f(h2)), l3 = f2bf(v.w - bf2f(h3));
        *(ushort4*)&Xhi[nd * XROW + k4 * 4] = make_ushort4(h0, h1, h2, h3);
        *(ushort4*)&Xlo[nd * XROW + k4 * 4] = make_ushort4(l0, l1, l2, l3);
    }
    __syncthreads();

    floatx4 acc[2][2] = {};
    #pragma unroll
    for (int u = 0; u < 2; ++u) {
        // B window: 4 hi + 4 lo frags for this u only (32 VGPRs)
        short8 bh[4], bl[4];
        const int j = (wv * 2 + u) * 16 + l16;
        #pragma unroll
        for (int c = 0; c < 4; ++c) {
            const int ko = c * 32 + quad * 8;
            bh[c] = *(const short8*)&WThi[j * 128 + ko];
            bl[c] = *(const short8*)&WTlo[j * 128 + ko];
        }
        #pragma unroll
        for (int c = 0; c < 4; ++c) {
            const int ko = c * 32 + quad * 8;
            #pragma unroll
            for (int r = 0; r < 2; ++r) {
                const short8 ah = *(const short8*)&Xhi[(r * 16 + l16) * XROW + ko];
                const short8 al = *(const short8*)&Xlo[(r * 16 + l16) * XROW + ko];
                acc[r][u] = __builtin_amdgcn_mfma_f32_16x16x32_bf16(ah, bl[c], acc[r][u], 0, 0, 0);
                acc[r][u] = __builtin_amdgcn_mfma_f32_16x16x32_bf16(al, bh[c], acc[r][u], 0, 0, 0);
                acc[r][u] = __builtin_amdgcn_mfma_f32_16x16x32_bf16(ah, bh[c], acc[r][u], 0, 0, 0);
            }
        }
    }

    // es/ed epilogue from fp32 acc (registers + shfl only)
    float asv[2], adv[2];
    #pragma unroll
    for (int u = 0; u < 2; ++u) {
        const int feat = (wv * 2 + u) * 16 + l16;
        asv[u] = a_src[feat];
        adv[u] = a_dst[feat];
    }
    #pragma unroll
    for (int r = 0; r < 2; ++r) {
        #pragma unroll
        for (int g = 0; g < 4; ++g) {
            float ps = acc[r][0][g] * asv[0] + acc[r][1][g] * asv[1];
            float pd = acc[r][0][g] * adv[0] + acc[r][1][g] * adv[1];
            #pragma unroll
            for (int o = 8; o >= 1; o >>= 1) {
                ps += __shfl_xor(ps, o);
                pd += __shfl_xor(pd, o);
            }
            const int node = node_base + r * 16 + quad * 4 + g;
            if (l16 == 0 && node < n) {
                es[node * 4 + wv] = ps;   // head == wv
                ed[node * 4 + wv] = pd;
            }
        }
    }

    // hb epilogue: transpose through LDS (reuse Xhi), then 2 uint4 stores
    __syncthreads();                       // done reading Xhi/Xlo
    unsigned short* T = Xhi;               // [32][128] row-major
    #pragma unroll
    for (int r = 0; r < 2; ++r)
    #pragma unroll
    for (int u = 0; u < 2; ++u) {
        const int feat = (wv * 2 + u) * 16 + l16;
        #pragma unroll
        for (int g = 0; g < 4; ++g)
            T[(r * 16 + quad * 4 + g) * 128 + feat] = f2bf(acc[r][u][g]);
    }
    __syncthreads();
    {
        const int row = t >> 3, seg = t & 7;   // row 0..31, seg 0..7 (16 feats)
        const int node = node_base + row;
        if (node < n) {
            const uint4 v0 = *(const uint4*)&T[row * 128 + seg * 16];
            const uint4 v1 = *(const uint4*)&T[row * 128 + seg * 16 + 8];
            *(uint4*)&hb[(size_t)node * 128 + seg * 16] = v0;
            *(uint4*)&hb[(size_t)node * 128 + seg * 16 + 8] = v1;
        }
    }
}

// ---------------------------------------------------------------------------
// sort_agg: one 512-thread block (8 waves) per 64-node region, exact region
// [r*RCAP, gcur[r*CPAD]). In-LDS counting sort over 64 local-dst values,
// then wave wv aggregates nodes wv*8..wv*8+7: 8 lanes/edge (lane owns 16
// feats), 16 edges in flight per wave. Same inner loop as the measured-60us
// r6/r8 form; fewer blocks/barriers per edge.
// ---------------------------------------------------------------------------
__global__ __launch_bounds__(512) void sort_agg_kernel(
    const unsigned short* __restrict__ hb, const float* __restrict__ es,
    const float* __restrict__ ed, const float* __restrict__ bias,
    const int* __restrict__ gcur, const int* __restrict__ ebuf,
    float* __restrict__ out, int n)
{
    __shared__ unsigned short esort[RCAP];
    __shared__ int hist[RNODES], hexcl[RNODES], cur[RNODES];
    const int b = blockIdx.x;
    const int t = threadIdx.x;
    const int lane = t & 63;
    const int wv = t >> 6;       // 0..7
    const int l8 = lane & 7;
    const int oct = lane >> 3;
    const int f0 = l8 * 16;      // this lane's 16 output features
    const int hh = l8 >> 1;      // head of those features (constant)

    const int start = b * RCAP;
    const int end = start + min(gcur[b * CPAD] - start, RCAP);

    if (t < RNODES) hist[t] = 0;
    __syncthreads();
    for (int i = start + t; i < end; i += 512)
        atomicAdd(&hist[(ebuf[i] >> 16) & (RNODES - 1)], 1);
    __syncthreads();
    if (wv == 0) {               // 64-lane scan over 64 node counts
        const int v = hist[lane];
        int incl = v;
        #pragma unroll
        for (int o = 1; o < RNODES; o <<= 1) {
            const int tt = __shfl_up(incl, o);
            if (lane >= o) incl += tt;
        }
        hexcl[lane] = incl - v;
        cur[lane] = incl - v;
    }
    __syncthreads();
    for (int i = start + t; i < end; i += 512) {
        const int v = ebuf[i];
        const int pos = atomicAdd(&cur[(v >> 16) & (RNODES - 1)], 1);
        if (pos < RCAP) esort[pos] = (unsigned short)(v & 0xFFFF);
    }
    __syncthreads();

    // aggregation: wave wv owns nodes wv*8 .. wv*8+7 (sequential)
    for (int j = 0; j < 8; ++j) {
        const int nd = wv * 8 + j;
        const int node = b * RNODES + nd;
        if (node >= n) break;
        const int off = hexcl[nd];
        const int deg = hist[nd];
        const float edh = ed[(size_t)node * 4 + hh];

        float a[16];
        #pragma unroll
        for (int k = 0; k < 16; ++k) a[k] = 0.f;
        float wsum = 0.f;

        for (int c0 = 0; c0 < deg; c0 += 16) {
            const int ci0 = c0 + oct;
            const int ci1 = ci0 + 8;
            const int dm = deg - 1;
            const int s0 = esort[min(off + min(ci0, dm), RCAP - 1)];
            const int s1 = esort[min(off + min(ci1, dm), RCAP - 1)];
            const float e0 = es[(size_t)s0 * 4 + hh];
            const float e1 = es[(size_t)s1 * 4 + hh];
            const uint4 hA0 = *(const uint4*)&hb[(size_t)s0 * 128 + f0];
            const uint4 hB0 = *(const uint4*)&hb[(size_t)s0 * 128 + f0 + 8];
            const uint4 hA1 = *(const uint4*)&hb[(size_t)s1 * 128 + f0];
            const uint4 hB1 = *(const uint4*)&hb[(size_t)s1 * 128 + f0 + 8];
            float lg0 = e0 + edh; lg0 = lg0 > 0.f ? lg0 : NEG_SLOPE * lg0;
            float lg1 = e1 + edh; lg1 = lg1 > 0.f ? lg1 : NEG_SLOPE * lg1;
            const float w0 = (ci0 < deg) ? __expf(lg0) : 0.f;
            const float w1 = (ci1 < deg) ? __expf(lg1) : 0.f;
            fma8(a, 0, w0, hA0); fma8(a, 8, w0, hB0);
            fma8(a, 0, w1, hA1); fma8(a, 8, w1, hB1);
            wsum += w0 + w1;
        }
        // combine the 8 octs
        #pragma unroll
        for (int o = 8; o <= 32; o <<= 1) {
            #pragma unroll
            for (int k = 0; k < 16; ++k) a[k] += __shfl_xor(a[k], o);
            wsum += __shfl_xor(wsum, o);
        }
        if (oct == 0) {
            const float inv = 1.f / ((wsum > 0.f) ? wsum : 1.f);
            #pragma unroll
            for (int q = 0; q < 4; ++q) {
                const float4 bq = *(const float4*)(bias + f0 + q * 4);
                float4 o4;
                o4.x = a[q * 4 + 0] * inv + bq.x;
                o4.y = a[q * 4 + 1] * inv + bq.y;
                o4.z = a[q * 4 + 2] * inv + bq.z;
                o4.w = a[q * 4 + 3] * inv + bq.w;
                *(float4*)(out + (size_t)node * 128 + f0 + q * 4) = o4;
            }
        }
    }
}

// ---------------------------------------------------------------------------
extern "C" void kernel_launch(void* const* d_in, const int* in_sizes, int n_in,
                              void* d_out, int out_size, void* d_ws, size_t ws_size,
                              hipStream_t stream)
{
    const float* x      = (const float*)d_in[0];
    const float* W      = (const float*)d_in[1];
    const float* a_src  = (const float*)d_in[2];
    const float* a_dst  = (const float*)d_in[3];
    const float* bias   = (const float*)d_in[4];
    const int*   e_src  = (const int*)d_in[5];
    const int*   e_dst  = (const int*)d_in[6];
    float* out = (float*)d_out;

    const int n = in_sizes[0] / 128;             // 50000 (< 65536: src fits 16b)
    const int e = in_sizes[5];                   // 1600000
    const int nreg = (n + RNODES - 1) >> RSHIFT; // 782 (< 1024: fits 10b)

    char* ws = (char*)d_ws;
    size_t o = 0;
    auto alloc = [&](size_t bytes) { void* p = ws + o; o += (bytes + 255) & ~(size_t)255; return p; };
    unsigned short* hb   = (unsigned short*)alloc((size_t)n * 128 * sizeof(unsigned short)); // 12.8 MB
    unsigned short* WThi = (unsigned short*)alloc(128 * 128 * sizeof(unsigned short));
    unsigned short* WTlo = (unsigned short*)alloc(128 * 128 * sizeof(unsigned short));
    float* es      = (float*)alloc((size_t)n * 4 * sizeof(float));
    float* ed      = (float*)alloc((size_t)n * 4 * sizeof(float));
    int* gcur      = (int*)alloc((size_t)nreg * CPAD * sizeof(int));   // 100 KB
    int* ebuf      = (int*)alloc((size_t)nreg * RCAP * sizeof(int));   // 7.6 MB
    (void)ws_size; (void)n_in; (void)out_size;

    prep_w_kernel<<<64, 256, 0, stream>>>(W, WThi, WTlo, gcur, nreg);
    scatter_kernel<<<NSB, 1024, 0, stream>>>(e_src, e_dst, gcur, ebuf, e, nreg);
    mfma_gemm_kernel<<<(n + 31) / 32, 256, 0, stream>>>(x, WThi, WTlo, a_src, a_dst,
                                                        hb, es, ed, n);
    sort_agg_kernel<<<nreg, 512, 0, stream>>>(hb, es, ed, bias, gcur, ebuf, out, n);
}